// Round 1
// baseline (1084.633 us; speedup 1.0000x reference)
//
#include <hip/hip_runtime.h>
#include <stdint.h>

#define HID 512
#define THREE_H 1536
#define ADIM 256
#define NVOC 10000
#define TEnc 256
#define TDec 128

typedef float f32x4 __attribute__((ext_vector_type(4)));
typedef __bf16 bf16x8 __attribute__((ext_vector_type(8)));

__device__ __forceinline__ unsigned short f2bf(float f) {
  union { float f; unsigned u; } v; v.f = f;
  unsigned r = v.u + 0x7FFFu + ((v.u >> 16) & 1u);
  return (unsigned short)(r >> 16);
}
__device__ __forceinline__ float sigmoidf_(float x) { return 1.f / (1.f + __expf(-x)); }
__device__ __forceinline__ float tanh_fast(float x) {
  float ax = fabsf(x);
  float e = __expf(ax + ax);
  float t = 1.f - 2.f / (e + 1.f);
  return copysignf(t, x);
}

#define GLDS16(gp, lp)                                                                 \
  __builtin_amdgcn_global_load_lds((const __attribute__((address_space(1))) void*)(gp),\
                                   (__attribute__((address_space(3))) void*)(lp), 16, 0, 0)

// ---------------- fp32 -> bf16 convert ----------------
__global__ void cvt_f32_bf16(const float* __restrict__ in, unsigned short* __restrict__ out, int n) {
  int i = (blockIdx.x * blockDim.x + threadIdx.x) * 4;
  if (i < n) {
    float4 v = *(const float4*)(in + i);
    ushort4 o;
    o.x = f2bf(v.x); o.y = f2bf(v.y); o.z = f2bf(v.z); o.w = f2bf(v.w);
    *(ushort4*)(out + i) = o;
  }
}

// ---------------- generic BT-GEMM: C[M,N] = A[M,K](bf16) * B[N,K]^T(f32->bf16) + bias ----------------
template <int BN, int BK>
__global__ __launch_bounds__(256, 1) void gemm_bt(
    const unsigned short* __restrict__ Abf, const float* __restrict__ B,
    const float* __restrict__ bias, float* __restrict__ C, unsigned short* __restrict__ Cbf,
    int M, int N, int K) {
  constexpr int NF = BN / 16;          // 16-col frags
  constexpr int B4 = BN * BK / 1024;   // float4 B-loads per thread
  constexpr int AG = BK / 16;          // glds issues per thread
  constexpr int KK = BK / 32;          // mfma k-steps per tile
  extern __shared__ char smem[];
  unsigned short* Al0 = (unsigned short*)smem;
  unsigned short* Al1 = Al0 + 128 * BK;
  unsigned short* Bl0 = Al1 + 128 * BK;
  unsigned short* Bl1 = Bl0 + BN * BK;

  const int tid = threadIdx.x;
  const int lane = tid & 63;
  const int wid = tid >> 6;
  const int m0 = blockIdx.x * 128;
  const int n0 = blockIdx.y * BN;
  const int NT = K / BK;

  float4 breg[B4];
  f32x4 acc[2][NF];
#pragma unroll
  for (int i = 0; i < 2; ++i)
#pragma unroll
    for (int j = 0; j < NF; ++j) acc[i][j] = (f32x4){0.f, 0.f, 0.f, 0.f};

  auto stageA = [&](int t, unsigned short* dst) {
    const unsigned short* Ab = Abf + (size_t)m0 * K + (size_t)t * BK;
#pragma unroll
    for (int g = 0; g < AG; ++g) {
      int elem = g * 2048 + tid * 8;
      int arow = elem / BK;
      int acol = elem - arow * BK;
      GLDS16(Ab + (size_t)arow * K + acol, (char*)dst + g * 4096 + wid * 1024);
    }
  };
  auto loadB = [&](int t) {
    const float* Bb = B + (size_t)t * BK;
#pragma unroll
    for (int p = 0; p < B4; ++p) {
      int e = (p * 256 + tid) * 4;
      int brow = e / BK;
      int bcol = e - brow * BK;
      int grow = n0 + brow;
      if (grow > N - 1) grow = N - 1;
      breg[p] = *(const float4*)(Bb + (size_t)grow * K + bcol);
    }
  };
  auto writeB = [&](unsigned short* dst) {
#pragma unroll
    for (int p = 0; p < B4; ++p) {
      ushort4 o;
      o.x = f2bf(breg[p].x); o.y = f2bf(breg[p].y);
      o.z = f2bf(breg[p].z); o.w = f2bf(breg[p].w);
      *(ushort4*)((char*)dst + (p * 256 + tid) * 8) = o;
    }
  };

  stageA(0, Al0);
  loadB(0);
  for (int t = 0; t < NT; ++t) {
    unsigned short* Ac = (t & 1) ? Al1 : Al0;
    unsigned short* Bc = (t & 1) ? Bl1 : Bl0;
    asm volatile("s_waitcnt vmcnt(0)" ::: "memory");  // A(t) in LDS, B(t) in regs
    writeB(Bc);
    __syncthreads();
    if (t + 1 < NT) {
      stageA(t + 1, (t & 1) ? Al0 : Al1);
      loadB(t + 1);
    }
    const int r0 = lane & 15;
    const int kb = (lane >> 4) * 8;
#pragma unroll
    for (int kk = 0; kk < KK; ++kk) {
      int ko = kk * 32 + kb;
      bf16x8 a0 = *(const bf16x8*)(Ac + (wid * 32 + r0) * BK + ko);
      bf16x8 a1 = *(const bf16x8*)(Ac + (wid * 32 + 16 + r0) * BK + ko);
#pragma unroll
      for (int nf = 0; nf < NF; ++nf) {
        bf16x8 bb = *(const bf16x8*)(Bc + (nf * 16 + r0) * BK + ko);
        acc[0][nf] = __builtin_amdgcn_mfma_f32_16x16x32_bf16(a0, bb, acc[0][nf], 0, 0, 0);
        acc[1][nf] = __builtin_amdgcn_mfma_f32_16x16x32_bf16(a1, bb, acc[1][nf], 0, 0, 0);
      }
    }
  }
  // epilogue: D layout col=lane&15, row=(lane>>4)*4+j  [m89-verified]
  const int cc = lane & 15;
  const int rq = (lane >> 4) * 4;
#pragma unroll
  for (int mi = 0; mi < 2; ++mi) {
    int row = m0 + wid * 32 + mi * 16 + rq;
#pragma unroll
    for (int nf = 0; nf < NF; ++nf) {
      int col = n0 + nf * 16 + cc;
      if (col < N) {
        float bv = bias ? bias[col] : 0.f;
#pragma unroll
        for (int j = 0; j < 4; ++j) {
          float v = acc[mi][nf][j] + bv;
          if (C) C[(size_t)(row + j) * N + col] = v;
          if (Cbf) Cbf[(size_t)(row + j) * N + col] = f2bf(v);
        }
      }
    }
  }
}

// ---------------- encoder gates (h_prev = 0) ----------------
__global__ __launch_bounds__(256) void enc_gate(const float* __restrict__ giX,
                                                const float* __restrict__ bie,
                                                const float* __restrict__ bhe,
                                                float* __restrict__ encH,
                                                unsigned short* __restrict__ encHbf) {
  int idx = blockIdx.x * 256 + threadIdx.x;  // 256*512 total
  int i = idx >> 9, j = idx & 511;
  const float* gi = giX + (size_t)i * THREE_H;
  float r = sigmoidf_(gi[j] + bie[j] + bhe[j]);
  float z = sigmoidf_(gi[HID + j] + bie[HID + j] + bhe[HID + j]);
  float n = tanh_fast(gi[2 * HID + j] + bie[2 * HID + j] + r * bhe[2 * HID + j]);
  float h = (1.f - z) * n;
  encH[idx] = h;
  encHbf[idx] = f2bf(h);
}

// ---------------- sequential GRU scan: 32 WGs, flag barrier per step ----------------
__global__ __launch_bounds__(256, 1) void gru_scan(
    const float* __restrict__ Whd, const float* __restrict__ bhd,
    const float* __restrict__ giY, const float* __restrict__ h0,
    float* __restrict__ hbuf, unsigned short* __restrict__ decSbf,
    unsigned short* __restrict__ concatbf, unsigned int* __restrict__ cnt) {
  extern __shared__ char smem[];
  float* WT = (float*)smem;        // k-major: WT4[k4*48 + row] = float4 of W[row][4k4..]
  float* hl = WT + 48 * 512;       // [512]
  float* dots = hl + 512;          // [48]
  const int g = blockIdx.x;
  const int tid = threadIdx.x;
  const int lane = tid & 63, wid = tid >> 6;

  for (int idx = tid * 4; idx < 48 * 512; idx += 1024) {
    int rr = idx >> 9;
    int ccl = idx & 511;
    int grow = (rr >> 4) * HID + g * 16 + (rr & 15);  // [r|z|n] row groups
    float4 w4 = *(const float4*)(Whd + (size_t)grow * HID + ccl);
    *(float4*)(WT + ((ccl >> 2) * 48 + rr) * 4) = w4;
  }
  __syncthreads();

  for (int t = 0; t < TDec; ++t) {
    const float* hsrc = (t == 0) ? h0 : (hbuf + ((t - 1) & 1) * HID);
    if (tid < 128) *(float4*)(hl + tid * 4) = *(const float4*)(hsrc + tid * 4);
    __syncthreads();
    if (wid < 3) {
      int row = wid * 16 + (lane & 15);
      int q = lane >> 4;
      const float4* wp = (const float4*)WT;
      const float4* hp = (const float4*)hl;
      float p = 0.f;
#pragma unroll 8
      for (int k4 = q * 32; k4 < q * 32 + 32; ++k4) {
        float4 wv = wp[k4 * 48 + row];
        float4 hv = hp[k4];
        p += wv.x * hv.x + wv.y * hv.y + wv.z * hv.z + wv.w * hv.w;
      }
      p += __shfl_xor(p, 16);
      p += __shfl_xor(p, 32);
      if (lane < 16) dots[row] = p;
    }
    __syncthreads();
    if (tid < 16) {
      int j = g * 16 + tid;
      const float* gi = giY + (size_t)t * THREE_H;
      float r = sigmoidf_(gi[j] + dots[tid] + bhd[j]);
      float z = sigmoidf_(gi[HID + j] + dots[16 + tid] + bhd[HID + j]);
      float n = tanh_fast(gi[2 * HID + j] + r * (dots[32 + tid] + bhd[2 * HID + j]));
      float hn = (1.f - z) * n + z * hl[j];
      hbuf[(t & 1) * HID + j] = hn;
      unsigned short hb = f2bf(hn);
      decSbf[(size_t)t * HID + j] = hb;
      concatbf[(size_t)t * 2 * HID + HID + j] = hb;
    }
    __threadfence();
    __syncthreads();
    if (tid == 0) {
      __hip_atomic_fetch_add(cnt, 1u, __ATOMIC_RELEASE, __HIP_MEMORY_SCOPE_AGENT);
      unsigned target = 32u * (unsigned)(t + 1);
      while (__hip_atomic_load(cnt, __ATOMIC_ACQUIRE, __HIP_MEMORY_SCOPE_AGENT) < target) {
        __builtin_amdgcn_s_sleep(1);
      }
    }
    __syncthreads();
  }
}

// ---------------- attention scores + softmax + context ----------------
__global__ __launch_bounds__(256) void attn_ctx(const float* __restrict__ encP,
                                                const float* __restrict__ decP,
                                                const float* __restrict__ vattn,
                                                const float* __restrict__ encH,
                                                unsigned short* __restrict__ concatbf) {
  __shared__ float dp[ADIM], vv[ADIM], pl[TEnc];
  __shared__ float red[8];
  const int t = blockIdx.x, tid = threadIdx.x;
  if (tid < 64) {
    *(float4*)(dp + tid * 4) = *(const float4*)(decP + (size_t)t * ADIM + tid * 4);
    *(float4*)(vv + tid * 4) = *(const float4*)(vattn + tid * 4);
  }
  __syncthreads();
  float s = 0.f;
  const float* ep = encP + (size_t)tid * ADIM;
#pragma unroll 4
  for (int a = 0; a < ADIM; a += 4) {
    float4 e4 = *(const float4*)(ep + a);
    s += vv[a] * tanh_fast(e4.x + dp[a]);
    s += vv[a + 1] * tanh_fast(e4.y + dp[a + 1]);
    s += vv[a + 2] * tanh_fast(e4.z + dp[a + 2]);
    s += vv[a + 3] * tanh_fast(e4.w + dp[a + 3]);
  }
  float m = s;
#pragma unroll
  for (int off = 32; off; off >>= 1) m = fmaxf(m, __shfl_xor(m, off));
  if ((tid & 63) == 0) red[tid >> 6] = m;
  __syncthreads();
  m = fmaxf(fmaxf(red[0], red[1]), fmaxf(red[2], red[3]));
  float p = __expf(s - m);
  pl[tid] = p;
  float sum = p;
#pragma unroll
  for (int off = 32; off; off >>= 1) sum += __shfl_xor(sum, off);
  if ((tid & 63) == 0) red[4 + (tid >> 6)] = sum;
  __syncthreads();
  float inv = 1.f / (red[4] + red[5] + red[6] + red[7]);
  float a0 = 0.f, a1 = 0.f;
  for (int e = 0; e < TEnc; ++e) {
    float pe = pl[e];
    a0 += pe * encH[(size_t)e * HID + tid];
    a1 += pe * encH[(size_t)e * HID + tid + 256];
  }
  concatbf[(size_t)t * 2 * HID + tid] = f2bf(a0 * inv);
  concatbf[(size_t)t * 2 * HID + tid + 256] = f2bf(a1 * inv);
}

extern "C" void kernel_launch(void* const* d_in, const int* in_sizes, int n_in,
                              void* d_out, int out_size, void* d_ws, size_t ws_size,
                              hipStream_t stream) {
  const float* x = (const float*)d_in[0];
  const float* y = (const float*)d_in[1];
  const float* Wi_e = (const float*)d_in[2];
  const float* bi_e = (const float*)d_in[4];
  const float* bh_e = (const float*)d_in[5];
  const float* Wi_d = (const float*)d_in[6];
  const float* Wh_d = (const float*)d_in[7];
  const float* bi_d = (const float*)d_in[8];
  const float* bh_d = (const float*)d_in[9];
  const float* Wh_attn = (const float*)d_in[10];
  const float* Ws_attn = (const float*)d_in[11];
  const float* b_attn = (const float*)d_in[12];
  const float* v_attn = (const float*)d_in[13];
  const float* W1 = (const float*)d_in[14];
  const float* b1 = (const float*)d_in[15];
  const float* W2 = (const float*)d_in[16];
  const float* b2 = (const float*)d_in[17];
  float* out = (float*)d_out;

  char* ws = (char*)d_ws;
  size_t off = 0;
  auto alloc = [&](size_t bytes) {
    char* p = ws + off;
    off += (bytes + 255) & ~(size_t)255;
    return p;
  };
  unsigned int* cnt = (unsigned int*)alloc(256);
  unsigned short* Xbf = (unsigned short*)alloc((size_t)TEnc * HID * 2);
  unsigned short* Ybf = (unsigned short*)alloc((size_t)TDec * HID * 2);
  float* giX = (float*)alloc((size_t)TEnc * THREE_H * 4);
  float* giY = (float*)alloc((size_t)TDec * THREE_H * 4);
  float* encH = (float*)alloc((size_t)TEnc * HID * 4);
  unsigned short* encHbf = (unsigned short*)alloc((size_t)TEnc * HID * 2);
  float* encP = (float*)alloc((size_t)TEnc * ADIM * 4);
  float* decP = (float*)alloc((size_t)TDec * ADIM * 4);
  unsigned short* decSbf = (unsigned short*)alloc((size_t)TDec * HID * 2);
  unsigned short* concatbf = (unsigned short*)alloc((size_t)TDec * 2 * HID * 2);
  unsigned short* out1bf = (unsigned short*)alloc((size_t)TDec * 20000 * 2);
  float* hbuf = (float*)alloc(2 * HID * 4);

  hipMemsetAsync(cnt, 0, 256, stream);

  // dynamic-LDS opt-in (>64KB); host-side, capture-safe
  auto* g32 = gemm_bt<32, 128>;
  auto* g80 = gemm_bt<80, 128>;
  auto* g64 = gemm_bt<64, 160>;
  const int smem32 = (128 + 32) * 128 * 2 * 2;   // 81920
  const int smem80 = (128 + 80) * 128 * 2 * 2;   // 106496
  const int smem64 = (128 + 64) * 160 * 2 * 2;   // 122880
  const int smemScan = (48 * 512 + 512 + 48) * 4;  // 100544
  hipFuncSetAttribute((const void*)g32, hipFuncAttributeMaxDynamicSharedMemorySize, smem32);
  hipFuncSetAttribute((const void*)g80, hipFuncAttributeMaxDynamicSharedMemorySize, smem80);
  hipFuncSetAttribute((const void*)g64, hipFuncAttributeMaxDynamicSharedMemorySize, smem64);
  hipFuncSetAttribute((const void*)gru_scan, hipFuncAttributeMaxDynamicSharedMemorySize, smemScan);

  cvt_f32_bf16<<<TEnc * HID / 1024, 256, 0, stream>>>(x, Xbf, TEnc * HID);
  cvt_f32_bf16<<<TDec * HID / 1024, 256, 0, stream>>>(y, Ybf, TDec * HID);

  // encoder: giX = Xbf @ Wi_e^T
  g32<<<dim3(2, 48), 256, smem32, stream>>>(Xbf, Wi_e, nullptr, giX, nullptr, 256, 1536, 512);
  enc_gate<<<TEnc * HID / 256, 256, 0, stream>>>(giX, bi_e, bh_e, encH, encHbf);
  // encP = encH @ Wh_attn^T
  g32<<<dim3(2, 8), 256, smem32, stream>>>(encHbf, Wh_attn, nullptr, encP, nullptr, 256, 256, 512);
  // giY = Ybf @ Wi_d^T + bi_d
  g32<<<dim3(1, 48), 256, smem32, stream>>>(Ybf, Wi_d, bi_d, giY, nullptr, 128, 1536, 512);
  // sequential decoder
  gru_scan<<<32, 256, smemScan, stream>>>(Wh_d, bh_d, giY, encH + 255 * HID, hbuf, decSbf, concatbf, cnt);
  // decP = decS @ Ws_attn^T + b_attn
  g32<<<dim3(1, 8), 256, smem32, stream>>>(decSbf, Ws_attn, b_attn, decP, nullptr, 128, 256, 512);
  attn_ctx<<<TDec, 256, 0, stream>>>(encP, decP, v_attn, encH, concatbf);
  // out1 = concat @ W1^T + b1 (store bf16)
  g80<<<dim3(1, 250), 256, smem80, stream>>>(concatbf, W1, b1, nullptr, out1bf, 128, 20000, 1024);
  // out = out1 @ W2^T + b2 (store f32 to d_out)
  g64<<<dim3(1, 157), 256, smem64, stream>>>(out1bf, W2, b2, out, nullptr, 128, 10000, 20000);
}

// Round 2
// 664.739 us; speedup vs baseline: 1.6317x; 1.6317x over previous
//
#include <hip/hip_runtime.h>
#include <stdint.h>

#define HID 512
#define THREE_H 1536
#define ADIM 256
#define NVOC 10000
#define TEnc 256
#define TDec 128

typedef float f32x4 __attribute__((ext_vector_type(4)));
typedef __bf16 bf16x8 __attribute__((ext_vector_type(8)));

__device__ __forceinline__ unsigned short f2bf(float f) {
  union { float f; unsigned u; } v; v.f = f;
  unsigned r = v.u + 0x7FFFu + ((v.u >> 16) & 1u);
  return (unsigned short)(r >> 16);
}
__device__ __forceinline__ float sigmoidf_(float x) { return 1.f / (1.f + __expf(-x)); }
__device__ __forceinline__ float tanh_fast(float x) {
  float ax = fabsf(x);
  float e = __expf(ax + ax);
  float t = 1.f - 2.f / (e + 1.f);
  return copysignf(t, x);
}

#define GLDS16(gp, lp)                                                                 \
  __builtin_amdgcn_global_load_lds((const __attribute__((address_space(1))) void*)(gp),\
                                   (__attribute__((address_space(3))) void*)(lp), 16, 0, 0)

// ---------------- fp32 -> bf16 convert ----------------
__global__ void cvt_f32_bf16(const float* __restrict__ in, unsigned short* __restrict__ out, int n) {
  int i = (blockIdx.x * blockDim.x + threadIdx.x) * 4;
  if (i < n) {
    float4 v = *(const float4*)(in + i);
    ushort4 o;
    o.x = f2bf(v.x); o.y = f2bf(v.y); o.z = f2bf(v.z); o.w = f2bf(v.w);
    *(ushort4*)(out + i) = o;
  }
}

// ---------------- generic BT-GEMM: C[M,N] = A[M,K](bf16) * B[N,K]^T(f32->bf16) + bias ----------------
template <int BN, int BK>
__global__ __launch_bounds__(256, 1) void gemm_bt(
    const unsigned short* __restrict__ Abf, const float* __restrict__ B,
    const float* __restrict__ bias, float* __restrict__ C, unsigned short* __restrict__ Cbf,
    int M, int N, int K) {
  constexpr int NF = BN / 16;          // 16-col frags
  constexpr int B4 = BN * BK / 1024;   // float4 B-loads per thread
  constexpr int AG = BK / 16;          // glds issues per thread
  constexpr int KK = BK / 32;          // mfma k-steps per tile
  extern __shared__ char smem[];
  unsigned short* Al0 = (unsigned short*)smem;
  unsigned short* Al1 = Al0 + 128 * BK;
  unsigned short* Bl0 = Al1 + 128 * BK;
  unsigned short* Bl1 = Bl0 + BN * BK;

  const int tid = threadIdx.x;
  const int lane = tid & 63;
  const int wid = tid >> 6;
  const int m0 = blockIdx.x * 128;
  const int n0 = blockIdx.y * BN;
  const int NT = K / BK;

  float4 breg[B4];
  f32x4 acc[2][NF];
#pragma unroll
  for (int i = 0; i < 2; ++i)
#pragma unroll
    for (int j = 0; j < NF; ++j) acc[i][j] = (f32x4){0.f, 0.f, 0.f, 0.f};

  auto stageA = [&](int t, unsigned short* dst) {
    const unsigned short* Ab = Abf + (size_t)m0 * K + (size_t)t * BK;
#pragma unroll
    for (int g = 0; g < AG; ++g) {
      int elem = g * 2048 + tid * 8;
      int arow = elem / BK;
      int acol = elem - arow * BK;
      GLDS16(Ab + (size_t)arow * K + acol, (char*)dst + g * 4096 + wid * 1024);
    }
  };
  auto loadB = [&](int t) {
    const float* Bb = B + (size_t)t * BK;
#pragma unroll
    for (int p = 0; p < B4; ++p) {
      int e = (p * 256 + tid) * 4;
      int brow = e / BK;
      int bcol = e - brow * BK;
      int grow = n0 + brow;
      if (grow > N - 1) grow = N - 1;
      breg[p] = *(const float4*)(Bb + (size_t)grow * K + bcol);
    }
  };
  auto writeB = [&](unsigned short* dst) {
#pragma unroll
    for (int p = 0; p < B4; ++p) {
      ushort4 o;
      o.x = f2bf(breg[p].x); o.y = f2bf(breg[p].y);
      o.z = f2bf(breg[p].z); o.w = f2bf(breg[p].w);
      *(ushort4*)((char*)dst + (p * 256 + tid) * 8) = o;
    }
  };

  stageA(0, Al0);
  loadB(0);
  for (int t = 0; t < NT; ++t) {
    unsigned short* Ac = (t & 1) ? Al1 : Al0;
    unsigned short* Bc = (t & 1) ? Bl1 : Bl0;
    asm volatile("s_waitcnt vmcnt(0)" ::: "memory");  // A(t) in LDS, B(t) in regs
    writeB(Bc);
    __syncthreads();
    if (t + 1 < NT) {
      stageA(t + 1, (t & 1) ? Al0 : Al1);
      loadB(t + 1);
    }
    const int r0 = lane & 15;
    const int kb = (lane >> 4) * 8;
#pragma unroll
    for (int kk = 0; kk < KK; ++kk) {
      int ko = kk * 32 + kb;
      bf16x8 a0 = *(const bf16x8*)(Ac + (wid * 32 + r0) * BK + ko);
      bf16x8 a1 = *(const bf16x8*)(Ac + (wid * 32 + 16 + r0) * BK + ko);
#pragma unroll
      for (int nf = 0; nf < NF; ++nf) {
        bf16x8 bb = *(const bf16x8*)(Bc + (nf * 16 + r0) * BK + ko);
        acc[0][nf] = __builtin_amdgcn_mfma_f32_16x16x32_bf16(a0, bb, acc[0][nf], 0, 0, 0);
        acc[1][nf] = __builtin_amdgcn_mfma_f32_16x16x32_bf16(a1, bb, acc[1][nf], 0, 0, 0);
      }
    }
  }
  // epilogue: D layout col=lane&15, row=(lane>>4)*4+j  [m89-verified]
  const int cc = lane & 15;
  const int rq = (lane >> 4) * 4;
#pragma unroll
  for (int mi = 0; mi < 2; ++mi) {
    int row = m0 + wid * 32 + mi * 16 + rq;
#pragma unroll
    for (int nf = 0; nf < NF; ++nf) {
      int col = n0 + nf * 16 + cc;
      if (col < N) {
        float bv = bias ? bias[col] : 0.f;
#pragma unroll
        for (int j = 0; j < 4; ++j) {
          float v = acc[mi][nf][j] + bv;
          if (C) C[(size_t)(row + j) * N + col] = v;
          if (Cbf) Cbf[(size_t)(row + j) * N + col] = f2bf(v);
        }
      }
    }
  }
}

// ---------------- encoder gates (h_prev = 0) ----------------
__global__ __launch_bounds__(256) void enc_gate(const float* __restrict__ giX,
                                                const float* __restrict__ bie,
                                                const float* __restrict__ bhe,
                                                float* __restrict__ encH,
                                                unsigned short* __restrict__ encHbf) {
  int idx = blockIdx.x * 256 + threadIdx.x;  // 256*512 total
  int i = idx >> 9, j = idx & 511;
  const float* gi = giX + (size_t)i * THREE_H;
  float r = sigmoidf_(gi[j] + bie[j] + bhe[j]);
  float z = sigmoidf_(gi[HID + j] + bie[HID + j] + bhe[HID + j]);
  float n = tanh_fast(gi[2 * HID + j] + bie[2 * HID + j] + r * bhe[2 * HID + j]);
  float h = (1.f - z) * n;
  encH[idx] = h;
  encHbf[idx] = f2bf(h);
}

// ---------------- sequential GRU scan, single-XCD cluster ----------------
// 256 WGs launched (1/CU via ~100KB LDS); each reads its XCC_ID and registers.
// First XCD to register 32 WGs wins; its WGs are the workers (slot 0..31),
// everyone else exits. All h-exchange then stays inside one coherent L2:
// packed (tag<<32 | f32bits) 64-bit volatile stores/loads — no fences, no
// device-scope atomics in the hot loop.
__global__ __launch_bounds__(256, 1) void gru_scan_xcd(
    const float* __restrict__ Whd, const float* __restrict__ bhd,
    const float* __restrict__ giY, const float* __restrict__ h0,
    unsigned long long* __restrict__ hx, unsigned int* __restrict__ cnt,
    unsigned int* __restrict__ winner,
    unsigned short* __restrict__ decSbf, unsigned short* __restrict__ concatbf) {
  extern __shared__ char smem[];
  float* WT = (float*)smem;        // k-major: WT4[k4*48 + row]
  float* hl = WT + 48 * 512;       // [512]
  float* dots = hl + 512;          // [48] + slot at int idx 48
  const int tid = threadIdx.x;
  const int lane = tid & 63, wid = tid >> 6;
  volatile int* slot_sh = (volatile int*)(dots + 52);

  // ---- election ----
  if (tid == 0) {
    unsigned xcd;
    asm volatile("s_getreg_b32 %0, hwreg(20, 0, 32)" : "=s"(xcd));
    xcd &= 7u;
    unsigned slot = atomicAdd(&cnt[xcd], 1u);  // device-scope
    if (slot == 31u) atomicCAS(winner, 0u, xcd + 1u);
    unsigned win = 0;
    if (slot < 32u) {
      int spin = 0;
      while ((win = __hip_atomic_load(winner, __ATOMIC_RELAXED,
                                      __HIP_MEMORY_SCOPE_AGENT)) == 0u &&
             ++spin < (1 << 20))
        __builtin_amdgcn_s_sleep(2);
    }
    *slot_sh = (slot < 32u && win == xcd + 1u) ? (int)slot : -1;
  }
  __syncthreads();
  const int g = *slot_sh;
  if (g < 0) return;  // not a worker

  // ---- stage weight slice: rows [r|z|n] x 16 dims, k-major float4 ----
  for (int idx = tid * 4; idx < 48 * 512; idx += 1024) {
    int rr = idx >> 9;
    int ccl = idx & 511;
    int grow = (rr >> 4) * HID + g * 16 + (rr & 15);
    float4 w4 = *(const float4*)(Whd + (size_t)grow * HID + ccl);
    *(float4*)(WT + ((ccl >> 2) * 48 + rr) * 4) = w4;
  }
  if (tid < 128) *(float4*)(hl + tid * 4) = *(const float4*)(h0 + tid * 4);
  __syncthreads();

  volatile unsigned long long* hxv = (volatile unsigned long long*)hx;

  for (int t = 0; t < TDec; ++t) {
    // dots = Wh_d[slice] @ h  (3 waves, 16 rows each, 2 half-K lanesets)
    if (wid < 3) {
      int row = wid * 16 + (lane & 15);
      int q = lane >> 4;
      const float4* wp = (const float4*)WT;
      const float4* hp = (const float4*)hl;
      float p = 0.f;
#pragma unroll 8
      for (int k4 = q * 32; k4 < q * 32 + 32; ++k4) {
        float4 wv = wp[k4 * 48 + row];
        float4 hv = hp[k4];
        p += wv.x * hv.x + wv.y * hv.y + wv.z * hv.z + wv.w * hv.w;
      }
      p += __shfl_xor(p, 16);
      p += __shfl_xor(p, 32);
      if (lane < 16) dots[row] = p;
    }
    __syncthreads();
    if (tid < 16) {
      int j = g * 16 + tid;
      const float* gi = giY + (size_t)t * THREE_H;
      float r = sigmoidf_(gi[j] + dots[tid] + bhd[j]);
      float z = sigmoidf_(gi[HID + j] + dots[16 + tid] + bhd[HID + j]);
      float n = tanh_fast(gi[2 * HID + j] + r * (dots[32 + tid] + bhd[2 * HID + j]));
      float hn = (1.f - z) * n + z * hl[j];
      // packed value+tag: single 8B store, naturally atomic, lands in XCD L2
      hxv[j] = ((unsigned long long)(unsigned)(t + 1) << 32) |
               (unsigned long long)__float_as_uint(hn);
      unsigned short hb = f2bf(hn);
      decSbf[(size_t)t * HID + j] = hb;
      concatbf[(size_t)t * 2 * HID + HID + j] = hb;
    }
    if (t == TDec - 1) break;
    __syncthreads();  // gate threads done reading hl before poll overwrites it
    // poll the full h vector (2 words/thread) from XCD-local L2
    unsigned long long w0, w1;
    int spin = 0;
    do { w0 = hxv[tid]; } while ((unsigned)(w0 >> 32) != (unsigned)(t + 1) && ++spin < (1 << 16));
    spin = 0;
    do { w1 = hxv[tid + 256]; } while ((unsigned)(w1 >> 32) != (unsigned)(t + 1) && ++spin < (1 << 16));
    hl[tid] = __uint_as_float((unsigned)w0);
    hl[tid + 256] = __uint_as_float((unsigned)w1);
    __syncthreads();
  }
}

// ---------------- attention scores + softmax + context ----------------
__global__ __launch_bounds__(256) void attn_ctx(const float* __restrict__ encP,
                                                const float* __restrict__ decP,
                                                const float* __restrict__ vattn,
                                                const float* __restrict__ encH,
                                                unsigned short* __restrict__ concatbf) {
  __shared__ float dp[ADIM], vv[ADIM], pl[TEnc];
  __shared__ float red[8];
  const int t = blockIdx.x, tid = threadIdx.x;
  if (tid < 64) {
    *(float4*)(dp + tid * 4) = *(const float4*)(decP + (size_t)t * ADIM + tid * 4);
    *(float4*)(vv + tid * 4) = *(const float4*)(vattn + tid * 4);
  }
  __syncthreads();
  float s = 0.f;
  const float* ep = encP + (size_t)tid * ADIM;
#pragma unroll 4
  for (int a = 0; a < ADIM; a += 4) {
    float4 e4 = *(const float4*)(ep + a);
    s += vv[a] * tanh_fast(e4.x + dp[a]);
    s += vv[a + 1] * tanh_fast(e4.y + dp[a + 1]);
    s += vv[a + 2] * tanh_fast(e4.z + dp[a + 2]);
    s += vv[a + 3] * tanh_fast(e4.w + dp[a + 3]);
  }
  float m = s;
#pragma unroll
  for (int off = 32; off; off >>= 1) m = fmaxf(m, __shfl_xor(m, off));
  if ((tid & 63) == 0) red[tid >> 6] = m;
  __syncthreads();
  m = fmaxf(fmaxf(red[0], red[1]), fmaxf(red[2], red[3]));
  float p = __expf(s - m);
  pl[tid] = p;
  float sum = p;
#pragma unroll
  for (int off = 32; off; off >>= 1) sum += __shfl_xor(sum, off);
  if ((tid & 63) == 0) red[4 + (tid >> 6)] = sum;
  __syncthreads();
  float inv = 1.f / (red[4] + red[5] + red[6] + red[7]);
  float a0 = 0.f, a1 = 0.f;
  for (int e = 0; e < TEnc; ++e) {
    float pe = pl[e];
    a0 += pe * encH[(size_t)e * HID + tid];
    a1 += pe * encH[(size_t)e * HID + tid + 256];
  }
  concatbf[(size_t)t * 2 * HID + tid] = f2bf(a0 * inv);
  concatbf[(size_t)t * 2 * HID + tid + 256] = f2bf(a1 * inv);
}

extern "C" void kernel_launch(void* const* d_in, const int* in_sizes, int n_in,
                              void* d_out, int out_size, void* d_ws, size_t ws_size,
                              hipStream_t stream) {
  const float* x = (const float*)d_in[0];
  const float* y = (const float*)d_in[1];
  const float* Wi_e = (const float*)d_in[2];
  const float* bi_e = (const float*)d_in[4];
  const float* bh_e = (const float*)d_in[5];
  const float* Wi_d = (const float*)d_in[6];
  const float* Wh_d = (const float*)d_in[7];
  const float* bi_d = (const float*)d_in[8];
  const float* bh_d = (const float*)d_in[9];
  const float* Wh_attn = (const float*)d_in[10];
  const float* Ws_attn = (const float*)d_in[11];
  const float* b_attn = (const float*)d_in[12];
  const float* v_attn = (const float*)d_in[13];
  const float* W1 = (const float*)d_in[14];
  const float* b1 = (const float*)d_in[15];
  const float* W2 = (const float*)d_in[16];
  const float* b2 = (const float*)d_in[17];
  float* out = (float*)d_out;

  char* ws = (char*)d_ws;
  size_t off = 0;
  auto alloc = [&](size_t bytes) {
    char* p = ws + off;
    off += (bytes + 255) & ~(size_t)255;
    return p;
  };
  // control region: zeroed every launch by ONE memset (replay-safe)
  char* ctrl = alloc(8192);
  unsigned long long* hx = (unsigned long long*)ctrl;          // 512*8 = 4096
  unsigned int* cnt = (unsigned int*)(ctrl + 4096);            // 8 counters
  unsigned int* winner = (unsigned int*)(ctrl + 4096 + 128);   // 1 word
  unsigned short* Xbf = (unsigned short*)alloc((size_t)TEnc * HID * 2);
  unsigned short* Ybf = (unsigned short*)alloc((size_t)TDec * HID * 2);
  float* giX = (float*)alloc((size_t)TEnc * THREE_H * 4);
  float* giY = (float*)alloc((size_t)TDec * THREE_H * 4);
  float* encH = (float*)alloc((size_t)TEnc * HID * 4);
  unsigned short* encHbf = (unsigned short*)alloc((size_t)TEnc * HID * 2);
  float* encP = (float*)alloc((size_t)TEnc * ADIM * 4);
  float* decP = (float*)alloc((size_t)TDec * ADIM * 4);
  unsigned short* decSbf = (unsigned short*)alloc((size_t)TDec * HID * 2);
  unsigned short* concatbf = (unsigned short*)alloc((size_t)TDec * 2 * HID * 2);
  unsigned short* out1bf = (unsigned short*)alloc((size_t)TDec * 20000 * 2);

  hipMemsetAsync(ctrl, 0, 8192, stream);

  auto* g32 = gemm_bt<32, 128>;
  auto* g80 = gemm_bt<80, 128>;
  auto* g64 = gemm_bt<64, 160>;
  const int smem32 = (128 + 32) * 128 * 2 * 2;     // 81920
  const int smem80 = (128 + 80) * 128 * 2 * 2;     // 106496
  const int smem64 = (128 + 64) * 160 * 2 * 2;     // 122880
  const int smemScan = (48 * 512 + 512 + 64) * 4;  // 100608
  hipFuncSetAttribute((const void*)g32, hipFuncAttributeMaxDynamicSharedMemorySize, smem32);
  hipFuncSetAttribute((const void*)g80, hipFuncAttributeMaxDynamicSharedMemorySize, smem80);
  hipFuncSetAttribute((const void*)g64, hipFuncAttributeMaxDynamicSharedMemorySize, smem64);
  hipFuncSetAttribute((const void*)gru_scan_xcd, hipFuncAttributeMaxDynamicSharedMemorySize, smemScan);

  cvt_f32_bf16<<<TEnc * HID / 1024, 256, 0, stream>>>(x, Xbf, TEnc * HID);
  cvt_f32_bf16<<<TDec * HID / 1024, 256, 0, stream>>>(y, Ybf, TDec * HID);

  // encoder: giX = Xbf @ Wi_e^T
  g32<<<dim3(2, 48), 256, smem32, stream>>>(Xbf, Wi_e, nullptr, giX, nullptr, 256, 1536, 512);
  enc_gate<<<TEnc * HID / 256, 256, 0, stream>>>(giX, bi_e, bh_e, encH, encHbf);
  // encP = encH @ Wh_attn^T
  g32<<<dim3(2, 8), 256, smem32, stream>>>(encHbf, Wh_attn, nullptr, encP, nullptr, 256, 256, 512);
  // giY = Ybf @ Wi_d^T + bi_d
  g32<<<dim3(1, 48), 256, smem32, stream>>>(Ybf, Wi_d, bi_d, giY, nullptr, 128, 1536, 512);
  // sequential decoder: single-XCD cluster scan
  gru_scan_xcd<<<256, 256, smemScan, stream>>>(Wh_d, bh_d, giY, encH + 255 * HID,
                                               hx, cnt, winner, decSbf, concatbf);
  // decP = decS @ Ws_attn^T + b_attn
  g32<<<dim3(1, 8), 256, smem32, stream>>>(decSbf, Ws_attn, b_attn, decP, nullptr, 128, 256, 512);
  attn_ctx<<<TDec, 256, 0, stream>>>(encP, decP, v_attn, encH, concatbf);
  // out1 = concat @ W1^T + b1 (store bf16)
  g80<<<dim3(1, 250), 256, smem80, stream>>>(concatbf, W1, b1, nullptr, out1bf, 128, 20000, 1024);
  // out = out1 @ W2^T + b2 (store f32 to d_out)
  g64<<<dim3(1, 157), 256, smem64, stream>>>(out1bf, W2, b2, out, nullptr, 128, 10000, 20000);
}